// Round 25
// baseline (100.537 us; speedup 1.0000x reference)
//
#include <hip/hip_runtime.h>
#include <math.h>

#define NG 8
#define SEQ 4096
#define DM 1024
#define NE 64
#define GS (NG * SEQ)          // 32768 tokens
#define KSEL 1024              // expert capacity
#define MASK_ELEMS (NE * GS)   // 2097152
#define SEG 16
#define SEGLEN (GS / SEG)
#define CAP 2048               // max repair candidates per expert
#define CAP2 16384             // max compacted entries per expert

typedef __attribute__((ext_vector_type(8))) short short8;
typedef __attribute__((ext_vector_type(4))) float f32x4;

__device__ __forceinline__ unsigned short f2bf(float v) {   // RN-even
  unsigned u = __float_as_uint(v);
  return (unsigned short)((u + 0x7FFFu + ((u >> 16) & 1u)) >> 16);
}
__device__ __forceinline__ float bf2f(unsigned short h) {
  return __uint_as_float(((unsigned)h) << 16);
}

// async global->LDS, 16B per lane (validated r22/r23)
#define GLDS(gsrc, ldst)                                                             \
  __builtin_amdgcn_global_load_lds(                                                  \
      (const __attribute__((address_space(1))) void*)(gsrc),                         \
      (__attribute__((address_space(3))) void*)(ldst), 16, 0, 0)

// ---------------- Kernel 0: weight split (wave-fragment order) + counter zeroing --
__global__ __launch_bounds__(256)
void k_split(const float* __restrict__ w, unsigned short* __restrict__ wph,
             unsigned short* __restrict__ wpm, unsigned* __restrict__ zbase) {
  const int t = blockIdx.x * 256 + threadIdx.x;
  if (t < NE * 256 + NE) zbase[t] = 0u;
  const int k = t >> 6, e = t & 63;
  float v = w[t];
  unsigned short h = f2bf(v); float r = v - bf2f(h);
  const int tile = k >> 5, g = (k >> 3) & 3, j = k & 7;
  const int cb = e >> 4, lrow = e & 15;
  const size_t o = (size_t)(tile * 4 + cb) * 512 + (g * 16 + lrow) * 8 + j;
  wph[o] = h; wpm[o] = f2bf(r);
}

// ---------------- Kernel 1: bf16x2 MFMA GEMM, DEPTH-4 async ring + fused hist -----
// r24 falsified channel-camping; the surviving theory for the ~65us wall is the
// max-latency TAIL of each load burst with only 2-deep pipelining (critical path
// = 16 x max-batch-latency, schedule-invariant). Fix: BK=32, ring of 4 buffers
// (64KB), steady-state s_waitcnt vmcnt(12) = waits on loads issued 3 steps back.
// Epilogue fuses hist0: per-block LDS histogram (reuses ring LDS) + sparse merge.
__global__ __launch_bounds__(256, 2)
void k_gemm_softmax(const float* __restrict__ x,
                    const unsigned short* __restrict__ wph,
                    const unsigned short* __restrict__ wpm,
                    const float* __restrict__ bias, const float* __restrict__ temp,
                    float* __restrict__ probsT, unsigned* __restrict__ ghist0) {
  __shared__ float S[16384];                 // 64 KB: 4 bufs x (A 8KB + B 8KB)
  unsigned* Su = (unsigned*)S;               // hist overlay [64][256] (64 KB)
  float (*Pt)[68] = (float (*)[68])S;        // transpose overlay (17.4 KB)

  const int tid = threadIdx.x;
  const int w = tid >> 6, lane = tid & 63;
  const int lrow = lane & 15, g = lane >> 4;
  const int m0 = blockIdx.x * 64;
  const int ks0 = blockIdx.x & 31;           // K-phase skew (kept; harmless)

#define TS(u) (((u) + ks0) & 31)

  // --- probes: C/D (lane,reg)->(i,j) for mfma_f32_16x16x32_bf16 (exact ints) ---
  int irow[4], jcol[4];
  {
    union { unsigned short u[8]; short8 v; } ar, on;
#pragma unroll
    for (int j = 0; j < 8; ++j) { ar.u[j] = f2bf((float)lrow); on.u[j] = 0x3F80u; }
    f32x4 z = {0.f, 0.f, 0.f, 0.f};
    f32x4 p1 = __builtin_amdgcn_mfma_f32_16x16x32_bf16(ar.v, on.v, z, 0, 0, 0);
    f32x4 p2 = __builtin_amdgcn_mfma_f32_16x16x32_bf16(on.v, ar.v, z, 0, 0, 0);
#pragma unroll
    for (int b = 0; b < 4; ++b) {
      irow[b] = ((int)p1[b]) >> 5;
      jcol[b] = ((int)p2[b]) >> 5;
    }
  }

  f32x4 acc[4];                              // [col-block], full-K accumulation
#pragma unroll
  for (int cb = 0; cb < 4; ++cb) acc[cb] = (f32x4){0.f, 0.f, 0.f, 0.f};

  // A image per buf: 512 granules of 16B; granule idx -> row=idx>>3, kg0=idx&7,
  // stores source k-granule kg0^(row&7) (bank-spread on frag reads, 2-way free).
  // B image per buf at +2048 floats: linear copy of tile s (frag-ordered planes).
#define ISSUE(s, buf)                                                                \
  {                                                                                  \
    _Pragma("unroll")                                                                \
    for (int c = 0; c < 2; ++c) {                                                    \
      const int idx = c * 256 + tid;                                                 \
      const int row = idx >> 3, kg = (idx & 7) ^ (row & 7);                          \
      GLDS(x + (size_t)(m0 + row) * DM + (s) * 32 + kg * 4,                          \
           S + (buf) * 4096 + idx * 4);                                              \
    }                                                                                \
    _Pragma("unroll")                                                                \
    for (int c = 0; c < 2; ++c) {                                                    \
      const int idx = c * 256 + tid;                                                 \
      const unsigned short* bp = (idx >> 8) ? wpm : wph;                             \
      GLDS(bp + (size_t)(s) * 2048 + (idx & 255) * 8,                                \
           S + (buf) * 4096 + 2048 + idx * 4);                                       \
    }                                                                                \
  }

#define COMPUTE(buf)                                                                 \
  {                                                                                  \
    const float* Af = S + (buf) * 4096;                                              \
    const unsigned short* Bb = (const unsigned short*)(S + (buf) * 4096 + 2048);     \
    const int row = w * 16 + lrow;                                                   \
    f32x4 lo = *(const f32x4*)(Af + row * 32 + ((g * 2 + 0) ^ (row & 7)) * 4);       \
    f32x4 hi = *(const f32x4*)(Af + row * 32 + ((g * 2 + 1) ^ (row & 7)) * 4);       \
    union { unsigned short u[8]; short8 v; } ah, am;                                 \
    _Pragma("unroll")                                                                \
    for (int j = 0; j < 8; ++j) {                                                    \
      float v0 = (j < 4) ? lo[j] : hi[j - 4];                                        \
      unsigned short h_ = f2bf(v0);                                                  \
      ah.u[j] = h_; am.u[j] = f2bf(v0 - bf2f(h_));                                   \
    }                                                                                \
    _Pragma("unroll")                                                                \
    for (int cb = 0; cb < 4; ++cb) {                                                 \
      short8 bh_ = *(const short8*)(Bb + cb * 512 + lane * 8);                       \
      short8 bm_ = *(const short8*)(Bb + 2048 + cb * 512 + lane * 8);                \
      acc[cb] = __builtin_amdgcn_mfma_f32_16x16x32_bf16(ah.v, bh_, acc[cb], 0, 0, 0);\
      acc[cb] = __builtin_amdgcn_mfma_f32_16x16x32_bf16(am.v, bh_, acc[cb], 0, 0, 0);\
      acc[cb] = __builtin_amdgcn_mfma_f32_16x16x32_bf16(ah.v, bm_, acc[cb], 0, 0, 0);\
    }                                                                                \
  }

#define WAITN(n) { asm volatile("s_waitcnt vmcnt(" #n ")" ::: "memory");             \
                   __builtin_amdgcn_sched_barrier(0); }

  ISSUE(TS(0), 0);
  ISSUE(TS(1), 1);
  ISSUE(TS(2), 2);
  ISSUE(TS(3), 3);
#pragma unroll
  for (int s = 0; s < 28; ++s) {
    WAITN(12);                               // step s landed (3 steps in flight)
    __builtin_amdgcn_s_barrier();            // all waves observed their loads
    COMPUTE(s & 3);
    __builtin_amdgcn_s_barrier();            // all waves done reading buf s&3
    ISSUE(TS(s + 4), s & 3);                 // refill; never drains the pipe
  }
  WAITN(12); __builtin_amdgcn_s_barrier(); COMPUTE(0);   // s=28
  WAITN(8);  __builtin_amdgcn_s_barrier(); COMPUTE(1);   // s=29
  WAITN(4);  __builtin_amdgcn_s_barrier(); COMPUTE(2);   // s=30
  WAITN(0);  __builtin_amdgcn_s_barrier(); COMPUTE(3);   // s=31
  __syncthreads();                           // all compute done before overlays

#undef ISSUE
#undef COMPUTE
#undef WAITN
#undef TS

  // --- softmax in-register -> pn[b][cb] ---
  float pn[4][4];
  {
    float st = temp[0];
    if (st < 0.1f) st = 0.1f;
    const float inv_t = 1.0f / st;
#pragma unroll
    for (int b = 0; b < 4; ++b) {
      float l[4];
      float mx = -1.0e30f;
#pragma unroll
      for (int cb = 0; cb < 4; ++cb) {
        l[cb] = (acc[cb][b] + bias[cb * 16 + jcol[b]]) * inv_t;
        mx = fmaxf(mx, l[cb]);
      }
      mx = fmaxf(mx, __shfl_xor(mx, 1));
      mx = fmaxf(mx, __shfl_xor(mx, 2));
      mx = fmaxf(mx, __shfl_xor(mx, 4));
      mx = fmaxf(mx, __shfl_xor(mx, 8));
      float p[4], sm = 0.0f;
#pragma unroll
      for (int cb = 0; cb < 4; ++cb) { p[cb] = __expf(l[cb] - mx); sm += p[cb]; }
      sm += __shfl_xor(sm, 1);
      sm += __shfl_xor(sm, 2);
      sm += __shfl_xor(sm, 4);
      sm += __shfl_xor(sm, 8);
      const float invs = 1.0f / sm;
#pragma unroll
      for (int cb = 0; cb < 4; ++cb) pn[b][cb] = p[cb] * invs;
    }
  }

  // --- fused hist0: per-block LDS histogram [expert][top-byte], sparse merge ---
  for (int i = tid; i < 16384; i += 256) Su[i] = 0u;
  __syncthreads();
#pragma unroll
  for (int b = 0; b < 4; ++b)
#pragma unroll
    for (int cb = 0; cb < 4; ++cb) {
      const int e = cb * 16 + jcol[b];
      atomicAdd(&Su[e * 256 + (__float_as_uint(pn[b][cb]) >> 24)], 1u);
    }
  __syncthreads();
  for (int i = tid; i < 16384; i += 256) {
    const unsigned h = Su[i];
    if (h) atomicAdd(&ghist0[i], h);
  }
  __syncthreads();

  // --- Pt transpose overlay + expert-major store ---
#pragma unroll
  for (int b = 0; b < 4; ++b)
#pragma unroll
    for (int cb = 0; cb < 4; ++cb)
      Pt[cb * 16 + jcol[b]][w * 16 + irow[b]] = pn[b][cb];
  __syncthreads();
  {
    const int e = tid >> 2, qq = tid & 3;
    float* dst = probsT + (size_t)e * GS + m0 + qq * 16;
#pragma unroll
    for (int c2 = 0; c2 < 4; ++c2)
      *(float4*)(dst + c2 * 4) = *(const float4*)(&Pt[e][qq * 16 + c2 * 4]);
  }
}

// ------------- cooperative bucket pick from a 256-bin histogram (block-wide) ------
__device__ __forceinline__ void pick_scan(const unsigned* __restrict__ bins,
                                          unsigned r_in, unsigned& bucket,
                                          unsigned& r_out, unsigned* res) {
  __syncthreads();
  const int tid = threadIdx.x;
  if (tid < 64) {
    uint4 b = ((const uint4*)bins)[tid];
    unsigned s3 = b.w, s2 = b.z + s3, s1 = b.y + s2, s0 = b.x + s1;
    unsigned suf = s0;
#pragma unroll
    for (int off = 1; off < 64; off <<= 1) {
      unsigned t = __shfl_down(suf, off);
      if (tid + off < 64) suf += t;
    }
    unsigned above = suf - s0;
    unsigned inc0 = above + s0, inc1 = above + s1, inc2 = above + s2, inc3 = above + s3;
    if (inc3 >= r_in && inc3 - b.w < r_in) { res[0] = 4 * tid + 3; res[1] = r_in - (inc3 - b.w); }
    if (inc2 >= r_in && inc2 - b.z < r_in) { res[0] = 4 * tid + 2; res[1] = r_in - (inc2 - b.z); }
    if (inc1 >= r_in && inc1 - b.y < r_in) { res[0] = 4 * tid + 1; res[1] = r_in - (inc1 - b.y); }
    if (inc0 >= r_in && inc0 - b.x < r_in) { res[0] = 4 * tid + 0; res[1] = r_in - (inc0 - b.x); }
  }
  __syncthreads();
  bucket = res[0];
  r_out = res[1];
}

// ---------------- Kernel 3: compact tokens with top-byte >= b0-1 ------------------
__global__ __launch_bounds__(256)
void k_compact(const float* __restrict__ probsT, const unsigned* __restrict__ ghist0,
               unsigned* __restrict__ cCnt, int* __restrict__ cIdx,
               float* __restrict__ cKey) {
  __shared__ unsigned res[2];
  __shared__ unsigned locN, basePos;
  __shared__ int locIdx[2048];
  __shared__ float locKey[2048];
  const int tid = threadIdx.x;
  const int e = blockIdx.x >> 4;
  const int seg = blockIdx.x & (SEG - 1);

  if (tid == 0) locN = 0u;
  unsigned b0, r0;
  pick_scan(ghist0 + e * 256, KSEL, b0, r0, res);
  const unsigned blo = (b0 == 0u) ? 0u : (b0 - 1u);

  const float* col = probsT + (size_t)e * GS + seg * SEGLEN;
  for (int i = 0; i < SEGLEN / 256; ++i) {
    const int t = i * 256 + tid;
    const float p = col[t];
    if ((__float_as_uint(p) >> 24) >= blo) {
      unsigned pos = atomicAdd(&locN, 1u);
      locIdx[pos] = seg * SEGLEN + t;
      locKey[pos] = p;
    }
  }
  __syncthreads();
  if (tid == 0) basePos = locN ? atomicAdd(&cCnt[e], locN) : 0u;
  __syncthreads();
  const unsigned n = locN, bp = basePos;
  for (unsigned i = tid; i < n; i += 256) {
    const unsigned gp = bp + i;
    if (gp < CAP2) {
      cIdx[(size_t)e * CAP2 + gp] = locIdx[i];
      cKey[(size_t)e * CAP2 + gp] = locKey[i];
    }
  }
}

// ---------------- Kernel 4: per-expert radix passes 1-3 + classify ----------------
__global__ __launch_bounds__(256)
void k_select2(const unsigned* __restrict__ ghist0, const unsigned* __restrict__ cCnt,
               const int* __restrict__ cIdx, const float* __restrict__ cKey,
               const float* __restrict__ temp, unsigned* __restrict__ defCnt,
               unsigned* __restrict__ candCnt, int* __restrict__ candIdx,
               float* __restrict__ thrHiA) {
  __shared__ unsigned res[2];
  __shared__ unsigned h[4][256];
  __shared__ unsigned hs[256];
  __shared__ unsigned nd, nc;
  const int tid = threadIdx.x, wv = tid >> 6;
  const int e = blockIdx.x;
  const int cnt = (int)min(cCnt[e], (unsigned)CAP2);

  unsigned b0, r;
  pick_scan(ghist0 + e * 256, KSEL, b0, r, res);
  unsigned pfx = b0 << 24;

  for (int pass = 1; pass < 4; ++pass) {
    const int shift = 24 - 8 * pass;
    const unsigned hm = 0xFFFFFFFFu << (shift + 8);
    for (int i = tid; i < 1024; i += 256) ((unsigned*)h)[i] = 0u;
    __syncthreads();
    for (int i = tid; i < cnt; i += 256) {
      unsigned key = __float_as_uint(cKey[(size_t)e * CAP2 + i]);
      if ((key & hm) == (pfx & hm)) atomicAdd(&h[wv][(key >> shift) & 255], 1u);
    }
    __syncthreads();
    hs[tid] = h[0][tid] + h[1][tid] + h[2][tid] + h[3][tid];
    unsigned b, rn;
    pick_scan(hs, r, b, rn, res);
    pfx |= b << shift;
    r = rn;
  }

  const float thrv = __uint_as_float(pfx);
  float st = temp[0];
  if (st < 0.1f) st = 0.1f;
  const float rel = 2.0e-3f / st;
  const float hi = thrv * (1.0f + rel);
  const float lo = thrv * (1.0f - rel);
  if (tid == 0) thrHiA[e] = hi;

  if (tid == 0) { nd = 0u; nc = 0u; }
  __syncthreads();
  for (int i = tid; i < cnt; i += 256) {
    const float p = cKey[(size_t)e * CAP2 + i];
    const int t = cIdx[(size_t)e * CAP2 + i];
    if (p > hi) {
      atomicAdd(&nd, 1u);
    } else if (p >= lo) {
      unsigned pos = atomicAdd(&nc, 1u);
      if (pos < CAP) candIdx[e * CAP + pos] = t;
    }
  }
  __syncthreads();
  if (tid == 0) {
    defCnt[e] = nd;
    candCnt[e] = min(nc, (unsigned)CAP);
  }
}

// ---------------- Kernel 5: exact fp64 recompute of candidate probabilities -------
__global__ __launch_bounds__(256)
void k_repair(const float* __restrict__ x, const float* __restrict__ w,
              const float* __restrict__ bias, const float* __restrict__ temp,
              const unsigned* __restrict__ candCnt, const int* __restrict__ candIdx,
              double* __restrict__ candKey) {
  __shared__ double red[4][64];
  const int e = blockIdx.x >> 4;
  const int chunk = blockIdx.x & 15;
  const int tid = threadIdx.x;
  const int ee = tid & 63, q = tid >> 6;
  const int cnt = (int)min(candCnt[e], (unsigned)CAP);

  double st = (double)temp[0];
  if (st < 0.1) st = 0.1;
  const double inv_t = 1.0 / st;

  for (int i = chunk; i < cnt; i += 16) {
    const int t = candIdx[e * CAP + i];
    const float* xr = x + (size_t)t * DM;
    double s0 = 0.0, s1 = 0.0, s2 = 0.0, s3 = 0.0;
    const int kb = q * 256;
    for (int k = kb; k < kb + 256; k += 4) {
      s0 += (double)xr[k + 0] * (double)w[(size_t)(k + 0) * NE + ee];
      s1 += (double)xr[k + 1] * (double)w[(size_t)(k + 1) * NE + ee];
      s2 += (double)xr[k + 2] * (double)w[(size_t)(k + 2) * NE + ee];
      s3 += (double)xr[k + 3] * (double)w[(size_t)(k + 3) * NE + ee];
    }
    red[q][ee] = (s0 + s1) + (s2 + s3);
    __syncthreads();
    if (tid < 64) {
      double l = (red[0][tid] + red[1][tid] + red[2][tid] + red[3][tid] +
                  (double)bias[tid]) * inv_t;
      double m = l;
#pragma unroll
      for (int off = 1; off < 64; off <<= 1) m = fmax(m, __shfl_xor(m, off));
      double ex = exp(l - m);
      double ss = ex;
#pragma unroll
      for (int off = 1; off < 64; off <<= 1) ss += __shfl_xor(ss, off);
      if (tid == e) candKey[e * CAP + i] = ex / ss;
    }
    __syncthreads();
  }
}

// ---------------- Kernel 6: dense mask scatter (definite region) + loss -----------
__global__ __launch_bounds__(256)
void k_scatter(const float* __restrict__ probsT, const float* __restrict__ thrHiA,
               float* __restrict__ out) {
  const int gid = blockIdx.x * 256 + threadIdx.x;
  const int base = gid * 4;
  const int e = base >> 15;
  float4 p = *(const float4*)(probsT + (size_t)base);
  const float hi = thrHiA[e];
  float pv[4] = {p.x, p.y, p.z, p.w};
  float mk[4], wt[4];
#pragma unroll
  for (int c = 0; c < 4; ++c) {
    bool sel = pv[c] > hi;
    mk[c] = sel ? 1.0f : 0.0f;
    wt[c] = sel ? pv[c] : 0.0f;
  }
  *(float4*)(out + (size_t)base) = make_float4(mk[0], mk[1], mk[2], mk[3]);
  *(float4*)(out + (size_t)MASK_ELEMS + base) = make_float4(wt[0], wt[1], wt[2], wt[3]);
  if (gid == 0) out[2 * (size_t)MASK_ELEMS] = 0.0f;
}

// ---------------- Kernel 7: rank candidates, patch selected into output -----------
__global__ __launch_bounds__(256)
void k_finish(const unsigned* __restrict__ defCnt, const unsigned* __restrict__ candCnt,
              const int* __restrict__ candIdx, const double* __restrict__ candKey,
              const float* __restrict__ probsT, float* __restrict__ out) {
  __shared__ double kd[CAP];
  __shared__ int ti[CAP];
  const int e = blockIdx.x, tid = threadIdx.x;
  const int cnt = (int)min(candCnt[e], (unsigned)CAP);
  const int need = KSEL - (int)defCnt[e];

  for (int i = tid; i < cnt; i += 256) {
    kd[i] = candKey[e * CAP + i];
    ti[i] = candIdx[e * CAP + i];
  }
  __syncthreads();
  for (int i = tid; i < cnt; i += 256) {
    const double ki = kd[i];
    const int tii = ti[i];
    int rank = 0;
    for (int j = 0; j < cnt; ++j)
      rank += (kd[j] > ki) || (kd[j] == ki && ti[j] < tii);
    if (rank < need) {
      out[(size_t)e * GS + tii] = 1.0f;
      out[(size_t)MASK_ELEMS + (size_t)e * GS + tii] = probsT[(size_t)e * GS + tii];
    }
  }
}

extern "C" void kernel_launch(void* const* d_in, const int* in_sizes, int n_in,
                              void* d_out, int out_size, void* d_ws, size_t ws_size,
                              hipStream_t stream) {
  const float* x    = (const float*)d_in[0];
  const float* gw   = (const float*)d_in[1];
  const float* gb   = (const float*)d_in[2];
  const float* temp = (const float*)d_in[3];

  float* probsT    = (float*)d_ws;                                        // 8MB
  unsigned* ghist0 = (unsigned*)((char*)d_ws + (size_t)MASK_ELEMS * 4);   // 64KB
  unsigned* cCnt   = ghist0 + NE * 256;                                   // 256B
  unsigned* defCnt = cCnt + NE;                                           // 256B
  unsigned* candCnt = defCnt + NE;                                        // 256B
  float* thrHiA    = (float*)(candCnt + NE);                              // 256B
  int* candIdx     = (int*)(thrHiA + NE);                                 // 512KB
  double* candKey  = (double*)(candIdx + NE * CAP);                       // 1MB
  int* cIdx        = (int*)(candKey + NE * CAP);                          // 4MB
  float* cKey      = (float*)(cIdx + (size_t)NE * CAP2);                  // 4MB
  unsigned short* wph = (unsigned short*)(cKey + (size_t)NE * CAP2);      // 128KB
  unsigned short* wpm = wph + DM * NE;                                    // 128KB

  k_split<<<DM * NE / 256, 256, 0, stream>>>(gw, wph, wpm, ghist0);
  k_gemm_softmax<<<GS / 64, 256, 0, stream>>>(x, wph, wpm, gb, temp, probsT,
                                              ghist0);
  k_compact<<<NE * SEG, 256, 0, stream>>>(probsT, ghist0, cCnt, cIdx, cKey);
  k_select2<<<NE, 256, 0, stream>>>(ghist0, cCnt, cIdx, cKey, temp, defCnt,
                                    candCnt, candIdx, thrHiA);
  k_repair<<<NE * 16, 256, 0, stream>>>(x, gw, gb, temp, candCnt, candIdx, candKey);
  k_scatter<<<MASK_ELEMS / 1024, 256, 0, stream>>>(probsT, thrHiA, (float*)d_out);
  k_finish<<<NE, 256, 0, stream>>>(defCnt, candCnt, candIdx, candKey,
                                   probsT, (float*)d_out);
}

// Round 26
// 93.516 us; speedup vs baseline: 1.0751x; 1.0751x over previous
//
#include <hip/hip_runtime.h>
#include <math.h>

#define NG 8
#define SEQ 4096
#define DM 1024
#define NE 64
#define GS (NG * SEQ)          // 32768 tokens
#define KSEL 1024              // expert capacity
#define MASK_ELEMS (NE * GS)   // 2097152
#define SEG 16
#define SEGLEN (GS / SEG)
#define CAP 2048               // max repair candidates per expert
#define CAP2 16384             // max compacted entries per expert

typedef __attribute__((ext_vector_type(8))) short short8;
typedef __attribute__((ext_vector_type(4))) float f32x4;

__device__ __forceinline__ unsigned short f2bf(float v) {   // RN-even
  unsigned u = __float_as_uint(v);
  return (unsigned short)((u + 0x7FFFu + ((u >> 16) & 1u)) >> 16);
}
__device__ __forceinline__ float bf2f(unsigned short h) {
  return __uint_as_float(((unsigned)h) << 16);
}

// async global->LDS, 16B per lane (validated r22/r23)
#define GLDS(gsrc, ldst)                                                             \
  __builtin_amdgcn_global_load_lds(                                                  \
      (const __attribute__((address_space(1))) void*)(gsrc),                         \
      (__attribute__((address_space(3))) void*)(ldst), 16, 0, 0)

// ---------------- Kernel 0: weight split (wave-fragment order) + counter zeroing --
__global__ __launch_bounds__(256)
void k_split(const float* __restrict__ w, unsigned short* __restrict__ wph,
             unsigned short* __restrict__ wpm, unsigned* __restrict__ zbase) {
  const int t = blockIdx.x * 256 + threadIdx.x;
  if (t < NE * 256 + NE) zbase[t] = 0u;
  const int k = t >> 6, e = t & 63;
  float v = w[t];
  unsigned short h = f2bf(v); float r = v - bf2f(h);
  const int tile = k >> 5, g = (k >> 3) & 3, j = k & 7;
  const int cb = e >> 4, lrow = e & 15;
  const size_t o = (size_t)(tile * 4 + cb) * 512 + (g * 16 + lrow) * 8 + j;
  wph[o] = h; wpm[o] = f2bf(r);
}

// ---------------- Kernel 1: BM=128 block-cooperative bf16x2 MFMA GEMM -------------
// Traffic ledger (r25): at BM=64, per-block B re-read (512x256KB=131MB) matched
// A's unique 134MB -> ~268MB at ~4TB/s = the 65us wall. BM=128 halves B traffic
// (256 blocks x 256KB = 65MB): total ~200MB. Skeleton = r23/r24 proven: 2-deep
// ring, global_load_lds, counted vmcnt(6), raw barriers, never drains. 512 thr /
// 8 waves, BK=64, wave owns 16 rows full-K (acc = 16 VGPRs). 96KB LDS, 1 blk/CU.
__global__ __launch_bounds__(512, 1)
void k_gemm_softmax(const float* __restrict__ x,
                    const unsigned short* __restrict__ wph,
                    const unsigned short* __restrict__ wpm,
                    const float* __restrict__ bias, const float* __restrict__ temp,
                    float* __restrict__ probsT) {
  __shared__ float S[24576];                 // 96 KB: 2 bufs x (A 32KB + B 16KB)
  float (*Pt)[132] = (float (*)[132])S;      // overlay after K-loop (33.8 KB)

  const int tid = threadIdx.x;
  const int w = tid >> 6, lane = tid & 63;
  const int lrow = lane & 15, g = lane >> 4;
  const int m0 = blockIdx.x * 128;

  // --- probes: C/D (lane,reg)->(i,j) for mfma_f32_16x16x32_bf16 (exact ints) ---
  int irow[4], jcol[4];
  {
    union { unsigned short u[8]; short8 v; } ar, on;
#pragma unroll
    for (int j = 0; j < 8; ++j) { ar.u[j] = f2bf((float)lrow); on.u[j] = 0x3F80u; }
    f32x4 z = {0.f, 0.f, 0.f, 0.f};
    f32x4 p1 = __builtin_amdgcn_mfma_f32_16x16x32_bf16(ar.v, on.v, z, 0, 0, 0);
    f32x4 p2 = __builtin_amdgcn_mfma_f32_16x16x32_bf16(on.v, ar.v, z, 0, 0, 0);
#pragma unroll
    for (int b = 0; b < 4; ++b) {
      irow[b] = ((int)p1[b]) >> 5;
      jcol[b] = ((int)p2[b]) >> 5;
    }
  }

  f32x4 acc[4];                              // [col-block], full-K accumulation
#pragma unroll
  for (int cb = 0; cb < 4; ++cb) acc[cb] = (f32x4){0.f, 0.f, 0.f, 0.f};

  // A image/buf: [128 rows][16 granules of 16B], granule grx holds source
  // k-granule grx^(row&15) (bank spread on frag reads). B image/buf at +8192
  // floats: linear copy of step's 8KB wph + 8KB wpm (frag-ordered planes).
#define ISSUE(s, buf)                                                                \
  {                                                                                  \
    _Pragma("unroll")                                                                \
    for (int c = 0; c < 4; ++c) {                                                    \
      const int idx = c * 512 + tid;                                                 \
      const int row = idx >> 4, kg = (idx & 15) ^ (row & 15);                        \
      GLDS(x + (size_t)(m0 + row) * DM + (s) * 64 + kg * 4,                          \
           S + (buf) * 12288 + idx * 4);                                             \
    }                                                                                \
    _Pragma("unroll")                                                                \
    for (int c = 0; c < 2; ++c) {                                                    \
      const int idx = c * 512 + tid;                                                 \
      const unsigned short* bp = (idx >> 9) ? wpm : wph;                             \
      GLDS(bp + (size_t)(s) * 4096 + (idx & 511) * 8,                                \
           S + (buf) * 12288 + 8192 + idx * 4);                                      \
    }                                                                                \
  }

#define COMPUTE(buf)                                                                 \
  {                                                                                  \
    const float* Af = S + (buf) * 12288;                                             \
    const unsigned short* Bb = (const unsigned short*)(S + (buf) * 12288 + 8192);    \
    const int row = w * 16 + lrow;                                                   \
    _Pragma("unroll")                                                                \
    for (int kt = 0; kt < 2; ++kt) {                                                 \
      f32x4 lo = *(const f32x4*)(Af + row * 64 +                                     \
                                 ((kt * 8 + g * 2 + 0) ^ (row & 15)) * 4);           \
      f32x4 hi = *(const f32x4*)(Af + row * 64 +                                     \
                                 ((kt * 8 + g * 2 + 1) ^ (row & 15)) * 4);           \
      union { unsigned short u[8]; short8 v; } ah, am;                               \
      _Pragma("unroll")                                                              \
      for (int j = 0; j < 8; ++j) {                                                  \
        float v0 = (j < 4) ? lo[j] : hi[j - 4];                                      \
        unsigned short h_ = f2bf(v0);                                                \
        ah.u[j] = h_; am.u[j] = f2bf(v0 - bf2f(h_));                                 \
      }                                                                              \
      _Pragma("unroll")                                                              \
      for (int cb = 0; cb < 4; ++cb) {                                               \
        short8 bh_ = *(const short8*)(Bb + (kt * 4 + cb) * 512 + lane * 8);          \
        short8 bm_ = *(const short8*)(Bb + 4096 + (kt * 4 + cb) * 512 + lane * 8);   \
        acc[cb] = __builtin_amdgcn_mfma_f32_16x16x32_bf16(ah.v, bh_, acc[cb], 0, 0, 0); \
        acc[cb] = __builtin_amdgcn_mfma_f32_16x16x32_bf16(am.v, bh_, acc[cb], 0, 0, 0); \
        acc[cb] = __builtin_amdgcn_mfma_f32_16x16x32_bf16(ah.v, bm_, acc[cb], 0, 0, 0); \
      }                                                                              \
    }                                                                                \
  }

#define WAITN(n) { asm volatile("s_waitcnt vmcnt(" #n ")" ::: "memory");             \
                   __builtin_amdgcn_sched_barrier(0); }

  ISSUE(0, 0);
  ISSUE(1, 1);
#pragma unroll
  for (int s = 0; s < 14; ++s) {
    WAITN(6);                                // step s landed (step s+1 in flight)
    __builtin_amdgcn_s_barrier();            // all waves observed their loads
    COMPUTE(s & 1);
    __builtin_amdgcn_s_barrier();            // all waves done reading buf s&1
    ISSUE(s + 2, s & 1);                     // refill; never drains the pipe
  }
  WAITN(6); __builtin_amdgcn_s_barrier(); COMPUTE(0);   // s=14
  __builtin_amdgcn_s_barrier();
  WAITN(0); __builtin_amdgcn_s_barrier(); COMPUTE(1);   // s=15
  __syncthreads();                           // full drain before Pt overlay

#undef ISSUE
#undef COMPUTE
#undef WAITN

  // --- softmax in-register; Pt[expert][token] via probe-measured mapping ---
  {
    float st = temp[0];
    if (st < 0.1f) st = 0.1f;
    const float inv_t = 1.0f / st;
#pragma unroll
    for (int b = 0; b < 4; ++b) {
      float l[4];
      float mx = -1.0e30f;
#pragma unroll
      for (int cb = 0; cb < 4; ++cb) {
        l[cb] = (acc[cb][b] + bias[cb * 16 + jcol[b]]) * inv_t;
        mx = fmaxf(mx, l[cb]);
      }
      mx = fmaxf(mx, __shfl_xor(mx, 1));
      mx = fmaxf(mx, __shfl_xor(mx, 2));
      mx = fmaxf(mx, __shfl_xor(mx, 4));
      mx = fmaxf(mx, __shfl_xor(mx, 8));
      float p[4], sm = 0.0f;
#pragma unroll
      for (int cb = 0; cb < 4; ++cb) { p[cb] = __expf(l[cb] - mx); sm += p[cb]; }
      sm += __shfl_xor(sm, 1);
      sm += __shfl_xor(sm, 2);
      sm += __shfl_xor(sm, 4);
      sm += __shfl_xor(sm, 8);
      const float invs = 1.0f / sm;
#pragma unroll
      for (int cb = 0; cb < 4; ++cb)
        Pt[cb * 16 + jcol[b]][w * 16 + irow[b]] = p[cb] * invs;
    }
  }
  __syncthreads();

  // --- expert-major store: 8 threads per expert, 128 tokens contiguous (512B) ---
  {
    const int e = tid >> 3, qq = tid & 7;
    float* dst = probsT + (size_t)e * GS + m0 + qq * 16;
#pragma unroll
    for (int c2 = 0; c2 < 4; ++c2)
      *(float4*)(dst + c2 * 4) = *(const float4*)(&Pt[e][qq * 16 + c2 * 4]);
  }
}

// ------------- cooperative bucket pick from a 256-bin histogram (block-wide) ------
__device__ __forceinline__ void pick_scan(const unsigned* __restrict__ bins,
                                          unsigned r_in, unsigned& bucket,
                                          unsigned& r_out, unsigned* res) {
  __syncthreads();
  const int tid = threadIdx.x;
  if (tid < 64) {
    uint4 b = ((const uint4*)bins)[tid];
    unsigned s3 = b.w, s2 = b.z + s3, s1 = b.y + s2, s0 = b.x + s1;
    unsigned suf = s0;
#pragma unroll
    for (int off = 1; off < 64; off <<= 1) {
      unsigned t = __shfl_down(suf, off);
      if (tid + off < 64) suf += t;
    }
    unsigned above = suf - s0;
    unsigned inc0 = above + s0, inc1 = above + s1, inc2 = above + s2, inc3 = above + s3;
    if (inc3 >= r_in && inc3 - b.w < r_in) { res[0] = 4 * tid + 3; res[1] = r_in - (inc3 - b.w); }
    if (inc2 >= r_in && inc2 - b.z < r_in) { res[0] = 4 * tid + 2; res[1] = r_in - (inc2 - b.z); }
    if (inc1 >= r_in && inc1 - b.y < r_in) { res[0] = 4 * tid + 1; res[1] = r_in - (inc1 - b.y); }
    if (inc0 >= r_in && inc0 - b.x < r_in) { res[0] = 4 * tid + 0; res[1] = r_in - (inc0 - b.x); }
  }
  __syncthreads();
  bucket = res[0];
  r_out = res[1];
}

// ---------------- Kernel 2: pass-0 (top-byte) histogram, full scan ----------------
__global__ __launch_bounds__(256)
void k_hist0(const float* __restrict__ probsT, unsigned* __restrict__ ghist0) {
  __shared__ unsigned h[4][256];
  const int tid = threadIdx.x, wv = tid >> 6;
  const int e = blockIdx.x >> 4;
  const int seg = blockIdx.x & (SEG - 1);
  h[0][tid] = 0; h[1][tid] = 0; h[2][tid] = 0; h[3][tid] = 0;
  __syncthreads();
  const float4* col = (const float4*)(probsT + (size_t)e * GS + seg * SEGLEN);
#pragma unroll
  for (int i = 0; i < SEGLEN / 1024; ++i) {
    float4 v = col[i * 256 + tid];
    atomicAdd(&h[wv][__float_as_uint(v.x) >> 24], 1u);
    atomicAdd(&h[wv][__float_as_uint(v.y) >> 24], 1u);
    atomicAdd(&h[wv][__float_as_uint(v.z) >> 24], 1u);
    atomicAdd(&h[wv][__float_as_uint(v.w) >> 24], 1u);
  }
  __syncthreads();
  unsigned c = h[0][tid] + h[1][tid] + h[2][tid] + h[3][tid];
  if (c) atomicAdd(&ghist0[e * 256 + tid], c);
}

// ---------------- Kernel 3: compact tokens with top-byte >= b0-1 ------------------
__global__ __launch_bounds__(256)
void k_compact(const float* __restrict__ probsT, const unsigned* __restrict__ ghist0,
               unsigned* __restrict__ cCnt, int* __restrict__ cIdx,
               float* __restrict__ cKey) {
  __shared__ unsigned res[2];
  __shared__ unsigned locN, basePos;
  __shared__ int locIdx[2048];
  __shared__ float locKey[2048];
  const int tid = threadIdx.x;
  const int e = blockIdx.x >> 4;
  const int seg = blockIdx.x & (SEG - 1);

  if (tid == 0) locN = 0u;
  unsigned b0, r0;
  pick_scan(ghist0 + e * 256, KSEL, b0, r0, res);
  const unsigned blo = (b0 == 0u) ? 0u : (b0 - 1u);

  const float* col = probsT + (size_t)e * GS + seg * SEGLEN;
  for (int i = 0; i < SEGLEN / 256; ++i) {
    const int t = i * 256 + tid;
    const float p = col[t];
    if ((__float_as_uint(p) >> 24) >= blo) {
      unsigned pos = atomicAdd(&locN, 1u);
      locIdx[pos] = seg * SEGLEN + t;
      locKey[pos] = p;
    }
  }
  __syncthreads();
  if (tid == 0) basePos = locN ? atomicAdd(&cCnt[e], locN) : 0u;
  __syncthreads();
  const unsigned n = locN, bp = basePos;
  for (unsigned i = tid; i < n; i += 256) {
    const unsigned gp = bp + i;
    if (gp < CAP2) {
      cIdx[(size_t)e * CAP2 + gp] = locIdx[i];
      cKey[(size_t)e * CAP2 + gp] = locKey[i];
    }
  }
}

// ---------------- Kernel 4: per-expert radix passes 1-3 + classify ----------------
__global__ __launch_bounds__(256)
void k_select2(const unsigned* __restrict__ ghist0, const unsigned* __restrict__ cCnt,
               const int* __restrict__ cIdx, const float* __restrict__ cKey,
               const float* __restrict__ temp, unsigned* __restrict__ defCnt,
               unsigned* __restrict__ candCnt, int* __restrict__ candIdx,
               float* __restrict__ thrHiA) {
  __shared__ unsigned res[2];
  __shared__ unsigned h[4][256];
  __shared__ unsigned hs[256];
  __shared__ unsigned nd, nc;
  const int tid = threadIdx.x, wv = tid >> 6;
  const int e = blockIdx.x;
  const int cnt = (int)min(cCnt[e], (unsigned)CAP2);

  unsigned b0, r;
  pick_scan(ghist0 + e * 256, KSEL, b0, r, res);
  unsigned pfx = b0 << 24;

  for (int pass = 1; pass < 4; ++pass) {
    const int shift = 24 - 8 * pass;
    const unsigned hm = 0xFFFFFFFFu << (shift + 8);
    for (int i = tid; i < 1024; i += 256) ((unsigned*)h)[i] = 0u;
    __syncthreads();
    for (int i = tid; i < cnt; i += 256) {
      unsigned key = __float_as_uint(cKey[(size_t)e * CAP2 + i]);
      if ((key & hm) == (pfx & hm)) atomicAdd(&h[wv][(key >> shift) & 255], 1u);
    }
    __syncthreads();
    hs[tid] = h[0][tid] + h[1][tid] + h[2][tid] + h[3][tid];
    unsigned b, rn;
    pick_scan(hs, r, b, rn, res);
    pfx |= b << shift;
    r = rn;
  }

  const float thrv = __uint_as_float(pfx);
  float st = temp[0];
  if (st < 0.1f) st = 0.1f;
  const float rel = 2.0e-3f / st;
  const float hi = thrv * (1.0f + rel);
  const float lo = thrv * (1.0f - rel);
  if (tid == 0) thrHiA[e] = hi;

  if (tid == 0) { nd = 0u; nc = 0u; }
  __syncthreads();
  for (int i = tid; i < cnt; i += 256) {
    const float p = cKey[(size_t)e * CAP2 + i];
    const int t = cIdx[(size_t)e * CAP2 + i];
    if (p > hi) {
      atomicAdd(&nd, 1u);
    } else if (p >= lo) {
      unsigned pos = atomicAdd(&nc, 1u);
      if (pos < CAP) candIdx[e * CAP + pos] = t;
    }
  }
  __syncthreads();
  if (tid == 0) {
    defCnt[e] = nd;
    candCnt[e] = min(nc, (unsigned)CAP);
  }
}

// ---------------- Kernel 5: exact fp64 recompute of candidate probabilities -------
__global__ __launch_bounds__(256)
void k_repair(const float* __restrict__ x, const float* __restrict__ w,
              const float* __restrict__ bias, const float* __restrict__ temp,
              const unsigned* __restrict__ candCnt, const int* __restrict__ candIdx,
              double* __restrict__ candKey) {
  __shared__ double red[4][64];
  const int e = blockIdx.x >> 4;
  const int chunk = blockIdx.x & 15;
  const int tid = threadIdx.x;
  const int ee = tid & 63, q = tid >> 6;
  const int cnt = (int)min(candCnt[e], (unsigned)CAP);

  double st = (double)temp[0];
  if (st < 0.1) st = 0.1;
  const double inv_t = 1.0 / st;

  for (int i = chunk; i < cnt; i += 16) {
    const int t = candIdx[e * CAP + i];
    const float* xr = x + (size_t)t * DM;
    double s0 = 0.0, s1 = 0.0, s2 = 0.0, s3 = 0.0;
    const int kb = q * 256;
    for (int k = kb; k < kb + 256; k += 4) {
      s0 += (double)xr[k + 0] * (double)w[(size_t)(k + 0) * NE + ee];
      s1 += (double)xr[k + 1] * (double)w[(size_t)(k + 1) * NE + ee];
      s2 += (double)xr[k + 2] * (double)w[(size_t)(k + 2) * NE + ee];
      s3 += (double)xr[k + 3] * (double)w[(size_t)(k + 3) * NE + ee];
    }
    red[q][ee] = (s0 + s1) + (s2 + s3);
    __syncthreads();
    if (tid < 64) {
      double l = (red[0][tid] + red[1][tid] + red[2][tid] + red[3][tid] +
                  (double)bias[tid]) * inv_t;
      double m = l;
#pragma unroll
      for (int off = 1; off < 64; off <<= 1) m = fmax(m, __shfl_xor(m, off));
      double ex = exp(l - m);
      double ss = ex;
#pragma unroll
      for (int off = 1; off < 64; off <<= 1) ss += __shfl_xor(ss, off);
      if (tid == e) candKey[e * CAP + i] = ex / ss;
    }
    __syncthreads();
  }
}

// ---------------- Kernel 6: dense mask scatter (definite region) + loss -----------
__global__ __launch_bounds__(256)
void k_scatter(const float* __restrict__ probsT, const float* __restrict__ thrHiA,
               float* __restrict__ out) {
  const int gid = blockIdx.x * 256 + threadIdx.x;
  const int base = gid * 4;
  const int e = base >> 15;
  float4 p = *(const float4*)(probsT + (size_t)base);
  const float hi = thrHiA[e];
  float pv[4] = {p.x, p.y, p.z, p.w};
  float mk[4], wt[4];
#pragma unroll
  for (int c = 0; c < 4; ++c) {
    bool sel = pv[c] > hi;
    mk[c] = sel ? 1.0f : 0.0f;
    wt[c] = sel ? pv[c] : 0.0f;
  }
  *(float4*)(out + (size_t)base) = make_float4(mk[0], mk[1], mk[2], mk[3]);
  *(float4*)(out + (size_t)MASK_ELEMS + base) = make_float4(wt[0], wt[1], wt[2], wt[3]);
  if (gid == 0) out[2 * (size_t)MASK_ELEMS] = 0.0f;
}

// ---------------- Kernel 7: rank candidates, patch selected into output -----------
__global__ __launch_bounds__(256)
void k_finish(const unsigned* __restrict__ defCnt, const unsigned* __restrict__ candCnt,
              const int* __restrict__ candIdx, const double* __restrict__ candKey,
              const float* __restrict__ probsT, float* __restrict__ out) {
  __shared__ double kd[CAP];
  __shared__ int ti[CAP];
  const int e = blockIdx.x, tid = threadIdx.x;
  const int cnt = (int)min(candCnt[e], (unsigned)CAP);
  const int need = KSEL - (int)defCnt[e];

  for (int i = tid; i < cnt; i += 256) {
    kd[i] = candKey[e * CAP + i];
    ti[i] = candIdx[e * CAP + i];
  }
  __syncthreads();
  for (int i = tid; i < cnt; i += 256) {
    const double ki = kd[i];
    const int tii = ti[i];
    int rank = 0;
    for (int j = 0; j < cnt; ++j)
      rank += (kd[j] > ki) || (kd[j] == ki && ti[j] < tii);
    if (rank < need) {
      out[(size_t)e * GS + tii] = 1.0f;
      out[(size_t)MASK_ELEMS + (size_t)e * GS + tii] = probsT[(size_t)e * GS + tii];
    }
  }
}

extern "C" void kernel_launch(void* const* d_in, const int* in_sizes, int n_in,
                              void* d_out, int out_size, void* d_ws, size_t ws_size,
                              hipStream_t stream) {
  const float* x    = (const float*)d_in[0];
  const float* gw   = (const float*)d_in[1];
  const float* gb   = (const float*)d_in[2];
  const float* temp = (const float*)d_in[3];

  float* probsT    = (float*)d_ws;                                        // 8MB
  unsigned* ghist0 = (unsigned*)((char*)d_ws + (size_t)MASK_ELEMS * 4);   // 64KB
  unsigned* cCnt   = ghist0 + NE * 256;                                   // 256B
  unsigned* defCnt = cCnt + NE;                                           // 256B
  unsigned* candCnt = defCnt + NE;                                        // 256B
  float* thrHiA    = (float*)(candCnt + NE);                              // 256B
  int* candIdx     = (int*)(thrHiA + NE);                                 // 512KB
  double* candKey  = (double*)(candIdx + NE * CAP);                       // 1MB
  int* cIdx        = (int*)(candKey + NE * CAP);                          // 4MB
  float* cKey      = (float*)(cIdx + (size_t)NE * CAP2);                  // 4MB
  unsigned short* wph = (unsigned short*)(cKey + (size_t)NE * CAP2);      // 128KB
  unsigned short* wpm = wph + DM * NE;                                    // 128KB

  k_split<<<DM * NE / 256, 256, 0, stream>>>(gw, wph, wpm, ghist0);
  k_gemm_softmax<<<GS / 128, 512, 0, stream>>>(x, wph, wpm, gb, temp, probsT);
  k_hist0<<<NE * SEG, 256, 0, stream>>>(probsT, ghist0);
  k_compact<<<NE * SEG, 256, 0, stream>>>(probsT, ghist0, cCnt, cIdx, cKey);
  k_select2<<<NE, 256, 0, stream>>>(ghist0, cCnt, cIdx, cKey, temp, defCnt,
                                    candCnt, candIdx, thrHiA);
  k_repair<<<NE * 16, 256, 0, stream>>>(x, gw, gb, temp, candCnt, candIdx, candKey);
  k_scatter<<<MASK_ELEMS / 1024, 256, 0, stream>>>(probsT, thrHiA, (float*)d_out);
  k_finish<<<NE, 256, 0, stream>>>(defCnt, candCnt, candIdx, candKey,
                                   probsT, (float*)d_out);
}

// Round 27
// 92.210 us; speedup vs baseline: 1.0903x; 1.0142x over previous
//
#include <hip/hip_runtime.h>
#include <math.h>

#define NG 8
#define SEQ 4096
#define DM 1024
#define NE 64
#define GS (NG * SEQ)          // 32768 tokens
#define KSEL 1024              // expert capacity
#define MASK_ELEMS (NE * GS)   // 2097152
#define SEG 16
#define SEGLEN (GS / SEG)
#define CAP 2048               // max repair candidates per expert
#define CAP2 16384             // max compacted entries per expert

typedef __attribute__((ext_vector_type(8))) short short8;
typedef __attribute__((ext_vector_type(4))) float f32x4;

__device__ __forceinline__ unsigned short f2bf(float v) {   // RN-even
  unsigned u = __float_as_uint(v);
  return (unsigned short)((u + 0x7FFFu + ((u >> 16) & 1u)) >> 16);
}
__device__ __forceinline__ float bf2f(unsigned short h) {
  return __uint_as_float(((unsigned)h) << 16);
}

// async global->LDS, 16B per lane (validated r22/r23)
#define GLDS(gsrc, ldst)                                                             \
  __builtin_amdgcn_global_load_lds(                                                  \
      (const __attribute__((address_space(1))) void*)(gsrc),                         \
      (__attribute__((address_space(3))) void*)(ldst), 16, 0, 0)

// ---------------- Kernel 0: weight split (wave-fragment order) + counter zeroing --
__global__ __launch_bounds__(256)
void k_split(const float* __restrict__ w, unsigned short* __restrict__ wph,
             unsigned short* __restrict__ wpm, unsigned* __restrict__ zbase) {
  const int t = blockIdx.x * 256 + threadIdx.x;
  if (t < NE * 256 + NE) zbase[t] = 0u;
  const int k = t >> 6, e = t & 63;
  float v = w[t];
  unsigned short h = f2bf(v); float r = v - bf2f(h);
  const int tile = k >> 5, g = (k >> 3) & 3, j = k & 7;
  const int cb = e >> 4, lrow = e & 15;
  const size_t o = (size_t)(tile * 4 + cb) * 512 + (g * 16 + lrow) * 8 + j;
  wph[o] = h; wpm[o] = f2bf(r);
}

// ---------------- Kernel 1: block-cooperative bf16x2 MFMA GEMM (r24 best config) --
// Final structure after 12 gemm rounds: BM=64, BK=64, 2-deep global_load_lds ring,
// counted vmcnt(8), raw s_barriers (never drains), K-phase skew. Eight structural
// theories tested/falsified; gemm is pattern-bandwidth-limited at ~3TB/s (~65us).
__global__ __launch_bounds__(256, 2)
void k_gemm_softmax(const float* __restrict__ x,
                    const unsigned short* __restrict__ wph,
                    const unsigned short* __restrict__ wpm,
                    const float* __restrict__ bias, const float* __restrict__ temp,
                    float* __restrict__ probsT) {
  __shared__ float S[16384];                 // 64 KB: 2 bufs x (A 16KB + B 16KB)
  float (*Pt)[68] = (float (*)[68])S;        // overlay after K-loop

  const int tid = threadIdx.x;
  const int w = tid >> 6, lane = tid & 63;
  const int lrow = lane & 15, g = lane >> 4;
  const int m0 = blockIdx.x * 64;
  const int ks0 = blockIdx.x & 15;           // K-phase skew

  const int arow_g = tid >> 4;               // staging row within 16-row stripe
  const int agr = (tid & 15) ^ (arow_g & 15);// swizzled k-granule for this thread

#define TS(u) (((u) + ks0) & 15)

  // --- probes: C/D (lane,reg)->(i,j) for mfma_f32_16x16x32_bf16 (exact ints) ---
  int irow[4], jcol[4];
  {
    union { unsigned short u[8]; short8 v; } ar, on;
#pragma unroll
    for (int j = 0; j < 8; ++j) { ar.u[j] = f2bf((float)lrow); on.u[j] = 0x3F80u; }
    f32x4 z = {0.f, 0.f, 0.f, 0.f};
    f32x4 p1 = __builtin_amdgcn_mfma_f32_16x16x32_bf16(ar.v, on.v, z, 0, 0, 0);
    f32x4 p2 = __builtin_amdgcn_mfma_f32_16x16x32_bf16(on.v, ar.v, z, 0, 0, 0);
#pragma unroll
    for (int b = 0; b < 4; ++b) {
      irow[b] = ((int)p1[b]) >> 5;
      jcol[b] = ((int)p2[b]) >> 5;
    }
  }

  f32x4 acc[4];                              // [col-block], full-K accumulation
#pragma unroll
  for (int cb = 0; cb < 4; ++cb) acc[cb] = (f32x4){0.f, 0.f, 0.f, 0.f};

#define ISSUE(s, buf)                                                                \
  {                                                                                  \
    _Pragma("unroll")                                                                \
    for (int c = 0; c < 4; ++c)                                                      \
      GLDS(x + (size_t)(m0 + c * 16 + arow_g) * DM + (s) * 64 + agr * 4,             \
           S + (buf) * 8192 + (c * 256 + tid) * 4);                                  \
    _Pragma("unroll")                                                                \
    for (int p = 0; p < 2; ++p)                                                      \
      _Pragma("unroll")                                                              \
      for (int c = 0; c < 2; ++c)                                                    \
        GLDS((p ? wpm : wph) + (size_t)(s) * 4096 + c * 2048 + tid * 8,              \
             S + (buf) * 8192 + 4096 + p * 2048 + c * 1024 + tid * 4);               \
  }

#define COMPUTE(buf)                                                                 \
  {                                                                                  \
    const float* Af = S + (buf) * 8192;                                              \
    const unsigned short* Bb = (const unsigned short*)(S + (buf) * 8192 + 4096);     \
    _Pragma("unroll")                                                                \
    for (int kt = 0; kt < 2; ++kt) {                                                 \
      f32x4 lo = *(const f32x4*)(Af + (w * 16 + lrow) * 64 +                         \
                                 ((kt * 8 + g * 2 + 0) ^ lrow) * 4);                 \
      f32x4 hi = *(const f32x4*)(Af + (w * 16 + lrow) * 64 +                         \
                                 ((kt * 8 + g * 2 + 1) ^ lrow) * 4);                 \
      union { unsigned short u[8]; short8 v; } ah, am;                               \
      _Pragma("unroll")                                                              \
      for (int j = 0; j < 8; ++j) {                                                  \
        float v0 = (j < 4) ? lo[j] : hi[j - 4];                                      \
        unsigned short h_ = f2bf(v0);                                                \
        ah.u[j] = h_; am.u[j] = f2bf(v0 - bf2f(h_));                                 \
      }                                                                              \
      _Pragma("unroll")                                                              \
      for (int cb = 0; cb < 4; ++cb) {                                               \
        short8 bh_ = *(const short8*)(Bb + (kt * 4 + cb) * 512 + lane * 8);          \
        short8 bm_ = *(const short8*)(Bb + 4096 + (kt * 4 + cb) * 512 + lane * 8);   \
        acc[cb] = __builtin_amdgcn_mfma_f32_16x16x32_bf16(ah.v, bh_, acc[cb], 0, 0, 0); \
        acc[cb] = __builtin_amdgcn_mfma_f32_16x16x32_bf16(am.v, bh_, acc[cb], 0, 0, 0); \
        acc[cb] = __builtin_amdgcn_mfma_f32_16x16x32_bf16(ah.v, bm_, acc[cb], 0, 0, 0); \
      }                                                                              \
    }                                                                                \
  }

#define WAIT8 { asm volatile("s_waitcnt vmcnt(8)" ::: "memory");                     \
                __builtin_amdgcn_sched_barrier(0); }
#define WAIT0 { asm volatile("s_waitcnt vmcnt(0)" ::: "memory");                     \
                __builtin_amdgcn_sched_barrier(0); }

  ISSUE(TS(0), 0);
  ISSUE(TS(1), 1);
#pragma unroll
  for (int s = 0; s < 14; ++s) {
    WAIT8;                                   // buf[s&1] (step s) fully landed
    __builtin_amdgcn_s_barrier();            // all waves see it; prev readers done
    if (s & 1) { COMPUTE(1); } else { COMPUTE(0); }
    __builtin_amdgcn_s_barrier();            // all waves done reading buf[s&1]
    ISSUE(TS(s + 2), s & 1);                 // refill; stays in flight (no drain)
  }
  WAIT8; __builtin_amdgcn_s_barrier(); COMPUTE(0);   // s=14
  __builtin_amdgcn_s_barrier();
  WAIT0; __builtin_amdgcn_s_barrier(); COMPUTE(1);   // s=15
  __syncthreads();                           // full drain before Pt overlay

#undef ISSUE
#undef COMPUTE
#undef WAIT8
#undef WAIT0
#undef TS

  // --- softmax in-register; Pt[expert][token] via probe-measured mapping ---
  {
    float st = temp[0];
    if (st < 0.1f) st = 0.1f;
    const float inv_t = 1.0f / st;
#pragma unroll
    for (int b = 0; b < 4; ++b) {
      float l[4];
      float mx = -1.0e30f;
#pragma unroll
      for (int cb = 0; cb < 4; ++cb) {
        l[cb] = (acc[cb][b] + bias[cb * 16 + jcol[b]]) * inv_t;
        mx = fmaxf(mx, l[cb]);
      }
      mx = fmaxf(mx, __shfl_xor(mx, 1));
      mx = fmaxf(mx, __shfl_xor(mx, 2));
      mx = fmaxf(mx, __shfl_xor(mx, 4));
      mx = fmaxf(mx, __shfl_xor(mx, 8));
      float p[4], sm = 0.0f;
#pragma unroll
      for (int cb = 0; cb < 4; ++cb) { p[cb] = __expf(l[cb] - mx); sm += p[cb]; }
      sm += __shfl_xor(sm, 1);
      sm += __shfl_xor(sm, 2);
      sm += __shfl_xor(sm, 4);
      sm += __shfl_xor(sm, 8);
      const float invs = 1.0f / sm;
#pragma unroll
      for (int cb = 0; cb < 4; ++cb)
        Pt[cb * 16 + jcol[b]][w * 16 + irow[b]] = p[cb] * invs;
    }
  }
  __syncthreads();

  // --- expert-major store: 4 threads per expert, 64 tokens contiguous (256B) ---
  {
    const int e = tid >> 2, qq = tid & 3;
    float* dst = probsT + (size_t)e * GS + m0 + qq * 16;
#pragma unroll
    for (int c2 = 0; c2 < 4; ++c2)
      *(float4*)(dst + c2 * 4) = *(const float4*)(&Pt[e][qq * 16 + c2 * 4]);
  }
}

// ------------- cooperative bucket pick from a 256-bin histogram (block-wide) ------
__device__ __forceinline__ void pick_scan(const unsigned* __restrict__ bins,
                                          unsigned r_in, unsigned& bucket,
                                          unsigned& r_out, unsigned* res) {
  __syncthreads();
  const int tid = threadIdx.x;
  if (tid < 64) {
    uint4 b = ((const uint4*)bins)[tid];
    unsigned s3 = b.w, s2 = b.z + s3, s1 = b.y + s2, s0 = b.x + s1;
    unsigned suf = s0;
#pragma unroll
    for (int off = 1; off < 64; off <<= 1) {
      unsigned t = __shfl_down(suf, off);
      if (tid + off < 64) suf += t;
    }
    unsigned above = suf - s0;
    unsigned inc0 = above + s0, inc1 = above + s1, inc2 = above + s2, inc3 = above + s3;
    if (inc3 >= r_in && inc3 - b.w < r_in) { res[0] = 4 * tid + 3; res[1] = r_in - (inc3 - b.w); }
    if (inc2 >= r_in && inc2 - b.z < r_in) { res[0] = 4 * tid + 2; res[1] = r_in - (inc2 - b.z); }
    if (inc1 >= r_in && inc1 - b.y < r_in) { res[0] = 4 * tid + 1; res[1] = r_in - (inc1 - b.y); }
    if (inc0 >= r_in && inc0 - b.x < r_in) { res[0] = 4 * tid + 0; res[1] = r_in - (inc0 - b.x); }
  }
  __syncthreads();
  bucket = res[0];
  r_out = res[1];
}

// ---------------- Kernel 2: pass-0 (top-byte) histogram, full scan ----------------
__global__ __launch_bounds__(256)
void k_hist0(const float* __restrict__ probsT, unsigned* __restrict__ ghist0) {
  __shared__ unsigned h[4][256];
  const int tid = threadIdx.x, wv = tid >> 6;
  const int e = blockIdx.x >> 4;
  const int seg = blockIdx.x & (SEG - 1);
  h[0][tid] = 0; h[1][tid] = 0; h[2][tid] = 0; h[3][tid] = 0;
  __syncthreads();
  const float4* col = (const float4*)(probsT + (size_t)e * GS + seg * SEGLEN);
#pragma unroll
  for (int i = 0; i < SEGLEN / 1024; ++i) {
    float4 v = col[i * 256 + tid];
    atomicAdd(&h[wv][__float_as_uint(v.x) >> 24], 1u);
    atomicAdd(&h[wv][__float_as_uint(v.y) >> 24], 1u);
    atomicAdd(&h[wv][__float_as_uint(v.z) >> 24], 1u);
    atomicAdd(&h[wv][__float_as_uint(v.w) >> 24], 1u);
  }
  __syncthreads();
  unsigned c = h[0][tid] + h[1][tid] + h[2][tid] + h[3][tid];
  if (c) atomicAdd(&ghist0[e * 256 + tid], c);
}

// ---------------- Kernel 3: compact tokens with top-byte >= b0-1 ------------------
__global__ __launch_bounds__(256)
void k_compact(const float* __restrict__ probsT, const unsigned* __restrict__ ghist0,
               unsigned* __restrict__ cCnt, int* __restrict__ cIdx,
               float* __restrict__ cKey) {
  __shared__ unsigned res[2];
  __shared__ unsigned locN, basePos;
  __shared__ int locIdx[2048];
  __shared__ float locKey[2048];
  const int tid = threadIdx.x;
  const int e = blockIdx.x >> 4;
  const int seg = blockIdx.x & (SEG - 1);

  if (tid == 0) locN = 0u;
  unsigned b0, r0;
  pick_scan(ghist0 + e * 256, KSEL, b0, r0, res);
  const unsigned blo = (b0 == 0u) ? 0u : (b0 - 1u);

  const float* col = probsT + (size_t)e * GS + seg * SEGLEN;
  for (int i = 0; i < SEGLEN / 256; ++i) {
    const int t = i * 256 + tid;
    const float p = col[t];
    if ((__float_as_uint(p) >> 24) >= blo) {
      unsigned pos = atomicAdd(&locN, 1u);
      locIdx[pos] = seg * SEGLEN + t;
      locKey[pos] = p;
    }
  }
  __syncthreads();
  if (tid == 0) basePos = locN ? atomicAdd(&cCnt[e], locN) : 0u;
  __syncthreads();
  const unsigned n = locN, bp = basePos;
  for (unsigned i = tid; i < n; i += 256) {
    const unsigned gp = bp + i;
    if (gp < CAP2) {
      cIdx[(size_t)e * CAP2 + gp] = locIdx[i];
      cKey[(size_t)e * CAP2 + gp] = locKey[i];
    }
  }
}

// ---------------- Kernel 4: per-expert radix passes 1-3 + classify ----------------
__global__ __launch_bounds__(256)
void k_select2(const unsigned* __restrict__ ghist0, const unsigned* __restrict__ cCnt,
               const int* __restrict__ cIdx, const float* __restrict__ cKey,
               const float* __restrict__ temp, unsigned* __restrict__ defCnt,
               unsigned* __restrict__ candCnt, int* __restrict__ candIdx,
               float* __restrict__ thrHiA) {
  __shared__ unsigned res[2];
  __shared__ unsigned h[4][256];
  __shared__ unsigned hs[256];
  __shared__ unsigned nd, nc;
  const int tid = threadIdx.x, wv = tid >> 6;
  const int e = blockIdx.x;
  const int cnt = (int)min(cCnt[e], (unsigned)CAP2);

  unsigned b0, r;
  pick_scan(ghist0 + e * 256, KSEL, b0, r, res);
  unsigned pfx = b0 << 24;

  for (int pass = 1; pass < 4; ++pass) {
    const int shift = 24 - 8 * pass;
    const unsigned hm = 0xFFFFFFFFu << (shift + 8);
    for (int i = tid; i < 1024; i += 256) ((unsigned*)h)[i] = 0u;
    __syncthreads();
    for (int i = tid; i < cnt; i += 256) {
      unsigned key = __float_as_uint(cKey[(size_t)e * CAP2 + i]);
      if ((key & hm) == (pfx & hm)) atomicAdd(&h[wv][(key >> shift) & 255], 1u);
    }
    __syncthreads();
    hs[tid] = h[0][tid] + h[1][tid] + h[2][tid] + h[3][tid];
    unsigned b, rn;
    pick_scan(hs, r, b, rn, res);
    pfx |= b << shift;
    r = rn;
  }

  const float thrv = __uint_as_float(pfx);
  float st = temp[0];
  if (st < 0.1f) st = 0.1f;
  const float rel = 2.0e-3f / st;
  const float hi = thrv * (1.0f + rel);
  const float lo = thrv * (1.0f - rel);
  if (tid == 0) thrHiA[e] = hi;

  if (tid == 0) { nd = 0u; nc = 0u; }
  __syncthreads();
  for (int i = tid; i < cnt; i += 256) {
    const float p = cKey[(size_t)e * CAP2 + i];
    const int t = cIdx[(size_t)e * CAP2 + i];
    if (p > hi) {
      atomicAdd(&nd, 1u);
    } else if (p >= lo) {
      unsigned pos = atomicAdd(&nc, 1u);
      if (pos < CAP) candIdx[e * CAP + pos] = t;
    }
  }
  __syncthreads();
  if (tid == 0) {
    defCnt[e] = nd;
    candCnt[e] = min(nc, (unsigned)CAP);
  }
}

// ---------------- Kernel 5: exact fp64 recompute of candidate probabilities -------
__global__ __launch_bounds__(256)
void k_repair(const float* __restrict__ x, const float* __restrict__ w,
              const float* __restrict__ bias, const float* __restrict__ temp,
              const unsigned* __restrict__ candCnt, const int* __restrict__ candIdx,
              double* __restrict__ candKey) {
  __shared__ double red[4][64];
  const int e = blockIdx.x >> 4;
  const int chunk = blockIdx.x & 15;
  const int tid = threadIdx.x;
  const int ee = tid & 63, q = tid >> 6;
  const int cnt = (int)min(candCnt[e], (unsigned)CAP);

  double st = (double)temp[0];
  if (st < 0.1) st = 0.1;
  const double inv_t = 1.0 / st;

  for (int i = chunk; i < cnt; i += 16) {
    const int t = candIdx[e * CAP + i];
    const float* xr = x + (size_t)t * DM;
    double s0 = 0.0, s1 = 0.0, s2 = 0.0, s3 = 0.0;
    const int kb = q * 256;
    for (int k = kb; k < kb + 256; k += 4) {
      s0 += (double)xr[k + 0] * (double)w[(size_t)(k + 0) * NE + ee];
      s1 += (double)xr[k + 1] * (double)w[(size_t)(k + 1) * NE + ee];
      s2 += (double)xr[k + 2] * (double)w[(size_t)(k + 2) * NE + ee];
      s3 += (double)xr[k + 3] * (double)w[(size_t)(k + 3) * NE + ee];
    }
    red[q][ee] = (s0 + s1) + (s2 + s3);
    __syncthreads();
    if (tid < 64) {
      double l = (red[0][tid] + red[1][tid] + red[2][tid] + red[3][tid] +
                  (double)bias[tid]) * inv_t;
      double m = l;
#pragma unroll
      for (int off = 1; off < 64; off <<= 1) m = fmax(m, __shfl_xor(m, off));
      double ex = exp(l - m);
      double ss = ex;
#pragma unroll
      for (int off = 1; off < 64; off <<= 1) ss += __shfl_xor(ss, off);
      if (tid == e) candKey[e * CAP + i] = ex / ss;
    }
    __syncthreads();
  }
}

// ---------------- Kernel 6: dense mask scatter (nontemporal streaming) ------------
__global__ __launch_bounds__(256)
void k_scatter(const float* __restrict__ probsT, const float* __restrict__ thrHiA,
               float* __restrict__ out) {
  const int gid = blockIdx.x * 256 + threadIdx.x;
  const int base = gid * 4;
  const int e = base >> 15;
  f32x4 p = __builtin_nontemporal_load((const f32x4*)(probsT + (size_t)base));
  const float hi = thrHiA[e];
  f32x4 mk, wt;
#pragma unroll
  for (int c = 0; c < 4; ++c) {
    bool sel = p[c] > hi;
    mk[c] = sel ? 1.0f : 0.0f;
    wt[c] = sel ? p[c] : 0.0f;
  }
  __builtin_nontemporal_store(mk, (f32x4*)(out + (size_t)base));
  __builtin_nontemporal_store(wt, (f32x4*)(out + (size_t)MASK_ELEMS + base));
  if (gid == 0) out[2 * (size_t)MASK_ELEMS] = 0.0f;
}

// ---------------- Kernel 7: rank candidates, patch selected into output -----------
__global__ __launch_bounds__(256)
void k_finish(const unsigned* __restrict__ defCnt, const unsigned* __restrict__ candCnt,
              const int* __restrict__ candIdx, const double* __restrict__ candKey,
              const float* __restrict__ probsT, float* __restrict__ out) {
  __shared__ double kd[CAP];
  __shared__ int ti[CAP];
  const int e = blockIdx.x, tid = threadIdx.x;
  const int cnt = (int)min(candCnt[e], (unsigned)CAP);
  const int need = KSEL - (int)defCnt[e];

  for (int i = tid; i < cnt; i += 256) {
    kd[i] = candKey[e * CAP + i];
    ti[i] = candIdx[e * CAP + i];
  }
  __syncthreads();
  for (int i = tid; i < cnt; i += 256) {
    const double ki = kd[i];
    const int tii = ti[i];
    int rank = 0;
    for (int j = 0; j < cnt; ++j)
      rank += (kd[j] > ki) || (kd[j] == ki && ti[j] < tii);
    if (rank < need) {
      out[(size_t)e * GS + tii] = 1.0f;
      out[(size_t)MASK_ELEMS + (size_t)e * GS + tii] = probsT[(size_t)e * GS + tii];
    }
  }
}

extern "C" void kernel_launch(void* const* d_in, const int* in_sizes, int n_in,
                              void* d_out, int out_size, void* d_ws, size_t ws_size,
                              hipStream_t stream) {
  const float* x    = (const float*)d_in[0];
  const float* gw   = (const float*)d_in[1];
  const float* gb   = (const float*)d_in[2];
  const float* temp = (const float*)d_in[3];

  float* probsT    = (float*)d_ws;                                        // 8MB
  unsigned* ghist0 = (unsigned*)((char*)d_ws + (size_t)MASK_ELEMS * 4);   // 64KB
  unsigned* cCnt   = ghist0 + NE * 256;                                   // 256B
  unsigned* defCnt = cCnt + NE;                                           // 256B
  unsigned* candCnt = defCnt + NE;                                        // 256B
  float* thrHiA    = (float*)(candCnt + NE);                              // 256B
  int* candIdx     = (int*)(thrHiA + NE);                                 // 512KB
  double* candKey  = (double*)(candIdx + NE * CAP);                       // 1MB
  int* cIdx        = (int*)(candKey + NE * CAP);                          // 4MB
  float* cKey      = (float*)(cIdx + (size_t)NE * CAP2);                  // 4MB
  unsigned short* wph = (unsigned short*)(cKey + (size_t)NE * CAP2);      // 128KB
  unsigned short* wpm = wph + DM * NE;                                    // 128KB

  k_split<<<DM * NE / 256, 256, 0, stream>>>(gw, wph, wpm, ghist0);
  k_gemm_softmax<<<GS / 64, 256, 0, stream>>>(x, wph, wpm, gb, temp, probsT);
  k_hist0<<<NE * SEG, 256, 0, stream>>>(probsT, ghist0);
  k_compact<<<NE * SEG, 256, 0, stream>>>(probsT, ghist0, cCnt, cIdx, cKey);
  k_select2<<<NE, 256, 0, stream>>>(ghist0, cCnt, cIdx, cKey, temp, defCnt,
                                    candCnt, candIdx, thrHiA);
  k_repair<<<NE * 16, 256, 0, stream>>>(x, gw, gb, temp, candCnt, candIdx, candKey);
  k_scatter<<<MASK_ELEMS / 1024, 256, 0, stream>>>(probsT, thrHiA, (float*)d_out);
  k_finish<<<NE, 256, 0, stream>>>(defCnt, candCnt, candIdx, candKey,
                                   probsT, (float*)d_out);
}